// Round 3
// baseline (2527.697 us; speedup 1.0000x reference)
//
#include <hip/hip_runtime.h>
#include <math.h>

#define HWD 1089
#define WD 33
#define NF 128
#define NJ 124
#define CC 32

__device__ __forceinline__ float sigm(float z) { return 1.f / (1.f + expf(-z)); }

// ---------------- rs[j] = sum_k mlp_w[j][k] ----------------
__global__ void rowsum_k(const float* __restrict__ mw, float* __restrict__ rs) {
    int j = blockIdx.x;
    const float* row = mw + (size_t)j * HWD;
    float s = 0.f;
    for (int k = threadIdx.x; k < HWD; k += 256) s += row[k];
    __shared__ float red[256];
    red[threadIdx.x] = s; __syncthreads();
    for (int off = 128; off > 0; off >>= 1) {
        if (threadIdx.x < off) red[threadIdx.x] += red[threadIdx.x + off];
        __syncthreads();
    }
    if (threadIdx.x == 0) rs[j] = red[0];
}

// ---------------- imgs = x * sigmoid((t/20)*rs + mlp_b) ----------------
__global__ void imgs_k(const float* __restrict__ x, const float* __restrict__ rs,
                       const float* __restrict__ mb, float* __restrict__ imgs) {
    int idx = blockIdx.x * 256 + threadIdx.x;
    if (idx >= NF * HWD) return;
    int t = idx / HWD, p = idx % HWD;
    float pe = sigm(((float)t / 20.0f) * rs[p] + mb[p]);
    imgs[idx] = x[idx] * pe;
}

// ---------------- 3x3 conv, NHWC in [n][p][CIN] -> out [n*ns + p*ps + o] ----------------
template <int CIN, int COUT, bool RELU, bool HAS_B, bool HAS_RES>
__global__ __launch_bounds__(256, 2)
void conv3x3_nhwc(const float* __restrict__ in,
                  const float* __restrict__ w, const float* __restrict__ b,
                  const float* __restrict__ res, int res_ps, int res_ns,
                  float* __restrict__ out, int out_ps, int out_ns, int N) {
    constexpr int WROW = (COUT + 3) & ~3;  // padded row for 16B-aligned LDS reads
    __shared__ float wl[9 * CIN * WROW];
    for (int i = threadIdx.x; i < 9 * CIN * WROW; i += 256) {
        int o = i % WROW, r = i / WROW;
        int c = r % CIN, k = r / CIN;
        wl[i] = (o < COUT) ? w[(o * CIN + c) * 9 + k] : 0.f;
    }
    __syncthreads();
    int idx = blockIdx.x * 256 + threadIdx.x;
    if (idx >= N * HWD) return;
    int n = idx / HWD, p = idx % HWD;
    int h = p / WD, q = p % WD;
    float acc[COUT];
#pragma unroll
    for (int o = 0; o < COUT; ++o) acc[o] = HAS_B ? b[o] : 0.f;
    const float* inn = in + (size_t)n * HWD * CIN;
#pragma unroll
    for (int k = 0; k < 9; ++k) {
        int hh = h + k / 3 - 1, qq = q + k % 3 - 1;
        if (hh < 0 || hh >= WD || qq < 0 || qq >= WD) continue;
        const float* ip = inn + (hh * WD + qq) * CIN;
        const float* wk = &wl[k * CIN * WROW];
#pragma unroll
        for (int cg = 0; cg < CIN / 4; ++cg) {
            float4 v = *(const float4*)(ip + cg * 4);
            const float* w0 = wk + (cg * 4) * WROW;
#pragma unroll
            for (int o = 0; o < COUT; ++o)
                acc[o] += v.x * w0[o] + v.y * w0[WROW + o]
                        + v.z * w0[2 * WROW + o] + v.w * w0[3 * WROW + o];
        }
    }
#pragma unroll
    for (int o = 0; o < COUT; ++o) {
        float val = acc[o];
        if (RELU) val = fmaxf(val, 0.f);
        if (HAS_RES) val += res[(size_t)n * res_ns + (size_t)p * res_ps + o];
        out[(size_t)n * out_ns + (size_t)p * out_ps + o] = val;
    }
}

// ---------------- 3x3 conv, CHW input (for fe 1->32 and tc0 5->32), NHWC out ----------------
template <int CIN, int COUT, bool RELU>
__global__ __launch_bounds__(256, 2)
void conv3x3_chwin(const float* __restrict__ in, int in_ns,
                   const float* __restrict__ w, const float* __restrict__ b,
                   float* __restrict__ out, int N) {
    __shared__ float wl[CIN * 9 * COUT];
    for (int i = threadIdx.x; i < CIN * 9 * COUT; i += 256) {
        int o = i % COUT, r = i / COUT;
        int k = r % 9, c = r / 9;
        wl[i] = w[(o * CIN + c) * 9 + k];
    }
    __syncthreads();
    int idx = blockIdx.x * 256 + threadIdx.x;
    if (idx >= N * HWD) return;
    int n = idx / HWD, p = idx % HWD;
    int h = p / WD, q = p % WD;
    float acc[COUT];
#pragma unroll
    for (int o = 0; o < COUT; ++o) acc[o] = b[o];
    const float* inn = in + (size_t)n * in_ns;
#pragma unroll
    for (int c = 0; c < CIN; ++c) {
#pragma unroll
        for (int k = 0; k < 9; ++k) {
            int hh = h + k / 3 - 1, qq = q + k % 3 - 1;
            if (hh < 0 || hh >= WD || qq < 0 || qq >= WD) continue;
            float v = inn[c * HWD + hh * WD + qq];
            const float* wp = &wl[(c * 9 + k) * COUT];
#pragma unroll
            for (int o = 0; o < COUT; ++o) acc[o] += v * wp[o];
        }
    }
    float* op = out + ((size_t)idx) * COUT;
#pragma unroll
    for (int o = 0; o < COUT; ++o) op[o] = RELU ? fmaxf(acc[o], 0.f) : acc[o];
}

// ---------------- a1c = 1x1 conv (16 out) of feats[n+2], NHWC ----------------
__global__ void a1c_k(const float* __restrict__ feats, const float* __restrict__ w,
                      const float* __restrict__ b, float* __restrict__ a1c) {
    __shared__ float wl[CC * 16];
    for (int i = threadIdx.x; i < CC * 16; i += 256) {
        int o = i % 16, c = i / 16;
        wl[i] = w[o * CC + c];
    }
    __syncthreads();
    int idx = blockIdx.x * 256 + threadIdx.x;
    if (idx >= NJ * HWD) return;
    int n = idx / HWD, p = idx % HWD;
    const float* f = feats + ((size_t)(n + 2) * HWD + p) * CC;
    float acc[16];
#pragma unroll
    for (int o = 0; o < 16; ++o) acc[o] = b[o];
#pragma unroll
    for (int cg = 0; cg < 8; ++cg) {
        float4 v = *(const float4*)(f + cg * 4);
        const float* w0 = &wl[cg * 4 * 16];
#pragma unroll
        for (int o = 0; o < 16; ++o)
            acc[o] += v.x * w0[o] + v.y * w0[16 + o] + v.z * w0[32 + o] + v.w * w0[48 + o];
    }
    float* op = a1c + (size_t)idx * 16;
#pragma unroll
    for (int o = 0; o < 16; o += 4)
        *(float4*)(op + o) = make_float4(acc[o], acc[o+1], acc[o+2], acc[o+3]);
}

// ---------------- a2 (1x1, NHWC) + agg=[mean,max] over concat(a1c,a2), NHWC ----------------
__global__ void a2agg_k(const float* __restrict__ feats, const float* __restrict__ w,
                        const float* __restrict__ b, const float* __restrict__ a1c,
                        float* __restrict__ a2, float* __restrict__ agg, int xoff) {
    __shared__ float wl[CC * 16];
    for (int i = threadIdx.x; i < CC * 16; i += 256) {
        int o = i % 16, c = i / 16;
        wl[i] = w[o * CC + c];
    }
    __syncthreads();
    int idx = blockIdx.x * 256 + threadIdx.x;
    if (idx >= NJ * HWD) return;
    int n = idx / HWD, p = idx % HWD;
    const float* f = feats + ((size_t)(n + xoff) * HWD + p) * CC;
    float acc[16];
#pragma unroll
    for (int o = 0; o < 16; ++o) acc[o] = b[o];
#pragma unroll
    for (int cg = 0; cg < 8; ++cg) {
        float4 v = *(const float4*)(f + cg * 4);
        const float* w0 = &wl[cg * 4 * 16];
#pragma unroll
        for (int o = 0; o < 16; ++o)
            acc[o] += v.x * w0[o] + v.y * w0[16 + o] + v.z * w0[32 + o] + v.w * w0[48 + o];
    }
    float sum = 0.f, mx = -1e30f;
    const float* ap = a1c + (size_t)idx * 16;
#pragma unroll
    for (int o = 0; o < 16; ++o) {
        float v = ap[o];
        sum += v; mx = fmaxf(mx, v);
    }
    float* op = a2 + (size_t)idx * 16;
#pragma unroll
    for (int o = 0; o < 16; ++o) {
        sum += acc[o]; mx = fmaxf(mx, acc[o]);
        op[o] = acc[o];
    }
    agg[(size_t)idx * 2 + 0] = sum * (1.f / 32.f);
    agg[(size_t)idx * 2 + 1] = mx;
}

// ---------------- sig = sigmoid(conv3x3(agg)); fused = [a1c*g0, a2*g1], NHWC ----------------
__global__ void sigfused_k(const float* __restrict__ agg, const float* __restrict__ sqw,
                           const float* __restrict__ sqb, const float* __restrict__ a1c,
                           const float* __restrict__ a2, float* __restrict__ fused) {
    int idx = blockIdx.x * 256 + threadIdx.x;
    if (idx >= NJ * HWD) return;
    int n = idx / HWD, p = idx % HWD;
    int h = p / WD, q = p % WD;
    float s0 = sqb[0], s1 = sqb[1];
    const float* ag = agg + (size_t)n * HWD * 2;
#pragma unroll
    for (int k = 0; k < 9; ++k) {
        int hh = h + k / 3 - 1, qq = q + k % 3 - 1;
        if (hh < 0 || hh >= WD || qq < 0 || qq >= WD) continue;
        float2 v = *(const float2*)(ag + (hh * WD + qq) * 2);
        s0 += v.x * sqw[0 * 18 + 0 * 9 + k] + v.y * sqw[0 * 18 + 1 * 9 + k];
        s1 += v.x * sqw[1 * 18 + 0 * 9 + k] + v.y * sqw[1 * 18 + 1 * 9 + k];
    }
    float g0 = sigm(s0), g1 = sigm(s1);
    const float* ap = a1c + (size_t)idx * 16;
    const float* bp = a2 + (size_t)idx * 16;
    float* fp = fused + (size_t)idx * CC;
#pragma unroll
    for (int o = 0; o < 16; ++o) fp[o] = ap[o] * g0;
#pragma unroll
    for (int o = 0; o < 16; ++o) fp[16 + o] = bp[o] * g1;
}

// ---------------- deformable conv 3x3, 32->32, NHWC ----------------
__global__ __launch_bounds__(256, 2)
void deform_k(const float* __restrict__ xbase, int xoff,
              const float* __restrict__ off, const float* __restrict__ w,
              float* __restrict__ out) {
    __shared__ float wl[9 * CC * CC];
    for (int i = threadIdx.x; i < 9 * CC * CC; i += 256) {
        int o = i & 31, c = (i >> 5) & 31, kk = i >> 10;
        wl[i] = w[(o * CC + c) * 9 + kk];
    }
    __syncthreads();
    int idx = blockIdx.x * 256 + threadIdx.x;
    if (idx >= NJ * HWD) return;
    int n = idx / HWD, p = idx % HWD;
    int h = p / WD, q = p % WD;
    const float* xf = xbase + (size_t)(n + xoff) * HWD * CC;
    const float* ofp = off + (size_t)idx * 18;
    float ofv[18];
#pragma unroll
    for (int i = 0; i < 18; i += 2) {
        float2 t = *(const float2*)(ofp + i);
        ofv[i] = t.x; ofv[i + 1] = t.y;
    }
    float acc[CC];
#pragma unroll
    for (int o = 0; o < CC; ++o) acc[o] = 0.f;
#pragma unroll
    for (int kk = 0; kk < 9; ++kk) {
        float py = (float)(h - 1 + kk / 3) + ofv[2 * kk];
        float px = (float)(q - 1 + kk % 3) + ofv[2 * kk + 1];
        float y0f = floorf(py), x0f = floorf(px);
        float ly = py - y0f, lx = px - x0f;
        int y0 = (int)y0f, x0 = (int)x0f;
        float w00 = (1.f - ly) * (1.f - lx), w01 = (1.f - ly) * lx;
        float w10 = ly * (1.f - lx), w11 = ly * lx;
        bool yv0 = (y0 >= 0 && y0 < WD), yv1 = (y0 + 1 >= 0 && y0 + 1 < WD);
        bool xv0 = (x0 >= 0 && x0 < WD), xv1 = (x0 + 1 >= 0 && x0 + 1 < WD);
        if (!(yv0 && xv0)) w00 = 0.f;
        if (!(yv0 && xv1)) w01 = 0.f;
        if (!(yv1 && xv0)) w10 = 0.f;
        if (!(yv1 && xv1)) w11 = 0.f;
        int yc0 = min(max(y0, 0), WD - 1), yc1 = min(max(y0 + 1, 0), WD - 1);
        int xc0 = min(max(x0, 0), WD - 1), xc1 = min(max(x0 + 1, 0), WD - 1);
        const float* p00 = xf + (yc0 * WD + xc0) * CC;
        const float* p01 = xf + (yc0 * WD + xc1) * CC;
        const float* p10 = xf + (yc1 * WD + xc0) * CC;
        const float* p11 = xf + (yc1 * WD + xc1) * CC;
        const float* wk = &wl[kk * CC * CC];
#pragma unroll
        for (int cg = 0; cg < 8; ++cg) {
            float4 a = *(const float4*)(p00 + cg * 4);
            float4 bb = *(const float4*)(p01 + cg * 4);
            float4 cc = *(const float4*)(p10 + cg * 4);
            float4 dd = *(const float4*)(p11 + cg * 4);
            float s0 = a.x * w00 + bb.x * w01 + cc.x * w10 + dd.x * w11;
            float s1 = a.y * w00 + bb.y * w01 + cc.y * w10 + dd.y * w11;
            float s2 = a.z * w00 + bb.z * w01 + cc.z * w10 + dd.z * w11;
            float s3 = a.w * w00 + bb.w * w01 + cc.w * w10 + dd.w * w11;
            const float* w0 = wk + (cg * 4) * CC;
#pragma unroll
            for (int o = 0; o < CC; ++o)
                acc[o] += s0 * w0[o] + s1 * w0[CC + o] + s2 * w0[2 * CC + o] + s3 * w0[3 * CC + o];
        }
    }
    float* op = out + (size_t)idx * CC;
#pragma unroll
    for (int o = 0; o < CC; o += 4)
        *(float4*)(op + o) = make_float4(acc[o], acc[o+1], acc[o+2], acc[o+3]);
}

// ---------------- cen_raw into aligned ch2 + arange output ----------------
__global__ void misc_k(const float* __restrict__ imgs, float* __restrict__ out) {
    int idx = blockIdx.x * 256 + threadIdx.x;
    float* alig = out + 135036 + 124;
    if (idx < NJ * HWD) {
        int n = idx / HWD, p = idx % HWD;
        alig[((size_t)n * 5 + 2) * HWD + p] = imgs[(size_t)(n + 2) * HWD + p];
    }
    if (idx < NJ) out[135036 + idx] = (float)(idx + 2);
}

extern "C" void kernel_launch(void* const* d_in, const int* in_sizes, int n_in,
                              void* d_out, int out_size, void* d_ws, size_t ws_size,
                              hipStream_t stream) {
    const float* x      = (const float*)d_in[0];
    const float* mlp_w  = (const float*)d_in[1];
    const float* mlp_b  = (const float*)d_in[2];
    const float* fe_w   = (const float*)d_in[3];
    const float* fe_b   = (const float*)d_in[4];
    const float* c0_w   = (const float*)d_in[5];
    const float* c0_b   = (const float*)d_in[6];
    const float* c1_w   = (const float*)d_in[7];
    const float* c1_b   = (const float*)d_in[8];
    const float* sq_w   = (const float*)d_in[9];
    const float* sq_b   = (const float*)d_in[10];
    const float* off1_w = (const float*)d_in[11];
    const float* off1_b = (const float*)d_in[12];
    const float* dw1    = (const float*)d_in[13];
    const float* off2_w = (const float*)d_in[14];
    const float* off2_b = (const float*)d_in[15];
    const float* dw2    = (const float*)d_in[16];
    const float* conv_w = (const float*)d_in[17];
    const float* conv_b = (const float*)d_in[18];
    const float* tc0_w  = (const float*)d_in[19];
    const float* tc0_b  = (const float*)d_in[20];
    const float* rb_w1  = (const float*)d_in[21];
    const float* rb_b1  = (const float*)d_in[22];
    const float* rb_w2  = (const float*)d_in[23];
    const float* rb_b2  = (const float*)d_in[24];
    const float* tail_w = (const float*)d_in[25];

    float* ws = (float*)d_ws;
    float* rs    = ws;                                   // 1089
    float* imgs  = rs + HWD;                             // NF*HWD
    float* feats = imgs + NF * HWD;                      // NF*HWD*32 (NHWC)
    float* a1c   = feats + (size_t)NF * HWD * CC;        // NJ*HWD*16 (NHWC)
    float* a2    = a1c + (size_t)NJ * HWD * 16;          // NJ*HWD*16
    float* agg   = a2 + (size_t)NJ * HWD * 16;           // NJ*HWD*2
    float* fused = agg + (size_t)NJ * HWD * 2;           // NJ*HWD*32 (also al2)
    float* offb  = fused + (size_t)NJ * HWD * CC;        // NJ*HWD*18
    float* al1   = offb + (size_t)NJ * HWD * 18;         // NJ*HWD*32
    float* hbuf  = feats;                                // reuse (NHWC)
    float* tmp   = a1c;                                  // reuse a1c+a2 (NJ*HWD*32)
    float* al2   = fused;

    float* outF = (float*)d_out;                         // final [0,135036)
    float* outA = outF + 135036 + 124;                   // aligned base (NCHW)

    const int GF = (NF * HWD + 255) / 256;
    const int GJ = (NJ * HWD + 255) / 256;

    rowsum_k<<<HWD, 256, 0, stream>>>(mlp_w, rs);
    imgs_k<<<GF, 256, 0, stream>>>(x, rs, mlp_b, imgs);
    conv3x3_chwin<1, 32, true><<<GF, 256, 0, stream>>>(imgs, HWD, fe_w, fe_b, feats, NF);
    a1c_k<<<GJ, 256, 0, stream>>>(feats, c0_w, c0_b, a1c);

    const int ioffs[4] = {-2, -1, 1, 2};
    const int cidx[4]  = {0, 1, 3, 4};
    for (int bi = 0; bi < 4; ++bi) {
        int xoff = 2 + ioffs[bi];
        a2agg_k<<<GJ, 256, 0, stream>>>(feats, c1_w, c1_b, a1c, a2, agg, xoff);
        sigfused_k<<<GJ, 256, 0, stream>>>(agg, sq_w, sq_b, a1c, a2, fused);
        conv3x3_nhwc<32, 18, false, true, false><<<GJ, 256, 0, stream>>>(
            fused, off1_w, off1_b, nullptr, 0, 0, offb, 18, HWD * 18, NJ);
        deform_k<<<GJ, 256, 0, stream>>>(feats, xoff, offb, dw1, al1);
        conv3x3_nhwc<32, 18, false, true, false><<<GJ, 256, 0, stream>>>(
            al1, off2_w, off2_b, nullptr, 0, 0, offb, 18, HWD * 18, NJ);
        deform_k<<<GJ, 256, 0, stream>>>(al1, 0, offb, dw2, al2);
        conv3x3_nhwc<32, 1, false, true, false><<<GJ, 256, 0, stream>>>(
            al2, conv_w, conv_b, nullptr, 0, 0, outA + cidx[bi] * HWD, 1, 5 * HWD, NJ);
    }

    misc_k<<<GJ, 256, 0, stream>>>(imgs, outF);

    conv3x3_chwin<5, 32, true><<<GJ, 256, 0, stream>>>(outA, 5 * HWD, tc0_w, tc0_b, hbuf, NJ);
    for (int l = 0; l < 5; ++l) {
        conv3x3_nhwc<32, 32, true, true, false><<<GJ, 256, 0, stream>>>(
            hbuf, rb_w1 + (size_t)l * CC * CC * 9, rb_b1 + l * CC,
            nullptr, 0, 0, tmp, CC, HWD * CC, NJ);
        conv3x3_nhwc<32, 32, false, true, true><<<GJ, 256, 0, stream>>>(
            tmp, rb_w2 + (size_t)l * CC * CC * 9, rb_b2 + l * CC,
            hbuf, CC, HWD * CC, hbuf, CC, HWD * CC, NJ);
    }
    conv3x3_nhwc<32, 1, false, false, false><<<GJ, 256, 0, stream>>>(
        hbuf, tail_w, nullptr, nullptr, 0, 0, outF, 1, HWD, NJ);
}

// Round 4
// 2042.045 us; speedup vs baseline: 1.2378x; 1.2378x over previous
//
#include <hip/hip_runtime.h>
#include <math.h>

#define HWD 1089
#define WD 33
#define NF 128
#define NJ 124
#define CC 32

__device__ __forceinline__ float sigm(float z) { return 1.f / (1.f + expf(-z)); }
__device__ __forceinline__ int sel4(int4 v, int i) { return i == 0 ? v.x : i == 1 ? v.y : i == 2 ? v.z : v.w; }

// ---------------- rs[j] = sum_k mlp_w[j][k] ----------------
__global__ void rowsum_k(const float* __restrict__ mw, float* __restrict__ rs) {
    int j = blockIdx.x;
    const float* row = mw + (size_t)j * HWD;
    float s = 0.f;
    for (int k = threadIdx.x; k < HWD; k += 256) s += row[k];
    __shared__ float red[256];
    red[threadIdx.x] = s; __syncthreads();
    for (int off = 128; off > 0; off >>= 1) {
        if (threadIdx.x < off) red[threadIdx.x] += red[threadIdx.x + off];
        __syncthreads();
    }
    if (threadIdx.x == 0) rs[j] = red[0];
}

// ---------------- imgs = x * sigmoid((t/20)*rs + mlp_b) ----------------
__global__ void imgs_k(const float* __restrict__ x, const float* __restrict__ rs,
                       const float* __restrict__ mb, float* __restrict__ imgs) {
    int idx = blockIdx.x * 256 + threadIdx.x;
    if (idx >= NF * HWD) return;
    int t = idx / HWD, p = idx % HWD;
    float pe = sigm(((float)t / 20.0f) * rs[p] + mb[p]);
    imgs[idx] = x[idx] * pe;
}

// ---------------- 3x3 conv, NHWC in -> NHWC-ish out (out_ps/out_ns strides) ----------------
template <int CIN, int COUT, bool RELU, bool HAS_B, bool HAS_RES>
__global__ __launch_bounds__(256, 2)
void conv3x3_nhwc(const float* __restrict__ in,
                  const float* __restrict__ w, const float* __restrict__ b,
                  const float* __restrict__ res, int res_ps, int res_ns,
                  float* __restrict__ out, int out_ps, int out_ns, int N) {
    constexpr int WROW = (COUT + 3) & ~3;
    __shared__ float wl[9 * CIN * WROW];
    for (int i = threadIdx.x; i < 9 * CIN * WROW; i += 256) {
        int o = i % WROW, r = i / WROW;
        int c = r % CIN, k = r / CIN;
        wl[i] = (o < COUT) ? w[(o * CIN + c) * 9 + k] : 0.f;
    }
    __syncthreads();
    int idx = blockIdx.x * 256 + threadIdx.x;
    if (idx >= N * HWD) return;
    int n = idx / HWD, p = idx % HWD;
    int h = p / WD, q = p % WD;
    float acc[COUT];
#pragma unroll
    for (int o = 0; o < COUT; ++o) acc[o] = HAS_B ? b[o] : 0.f;
    const float* inn = in + (size_t)n * HWD * CIN;
#pragma unroll
    for (int k = 0; k < 9; ++k) {
        int hh = h + k / 3 - 1, qq = q + k % 3 - 1;
        if (hh < 0 || hh >= WD || qq < 0 || qq >= WD) continue;
        const float* ip = inn + (hh * WD + qq) * CIN;
        const float* wk = &wl[k * CIN * WROW];
#pragma unroll
        for (int cg = 0; cg < CIN / 4; ++cg) {
            float4 v = *(const float4*)(ip + cg * 4);
            const float* w0 = wk + (cg * 4) * WROW;
#pragma unroll
            for (int o = 0; o < COUT; ++o)
                acc[o] += v.x * w0[o] + v.y * w0[WROW + o]
                        + v.z * w0[2 * WROW + o] + v.w * w0[3 * WROW + o];
        }
    }
#pragma unroll
    for (int o = 0; o < COUT; ++o) {
        float val = acc[o];
        if (RELU) val = fmaxf(val, 0.f);
        if (HAS_RES) val += res[(size_t)n * res_ns + (size_t)p * res_ps + o];
        out[(size_t)n * out_ns + (size_t)p * out_ps + o] = val;
    }
}

// ---------------- 3x3 conv, CHW input (fe 1->32, tc0 5->32), NHWC out ----------------
template <int CIN, int COUT, bool RELU>
__global__ __launch_bounds__(256, 2)
void conv3x3_chwin(const float* __restrict__ in, int in_ns,
                   const float* __restrict__ w, const float* __restrict__ b,
                   float* __restrict__ out, int N) {
    __shared__ float wl[CIN * 9 * COUT];
    for (int i = threadIdx.x; i < CIN * 9 * COUT; i += 256) {
        int o = i % COUT, r = i / COUT;
        int k = r % 9, c = r / 9;
        wl[i] = w[(o * CIN + c) * 9 + k];
    }
    __syncthreads();
    int idx = blockIdx.x * 256 + threadIdx.x;
    if (idx >= N * HWD) return;
    int n = idx / HWD, p = idx % HWD;
    int h = p / WD, q = p % WD;
    float acc[COUT];
#pragma unroll
    for (int o = 0; o < COUT; ++o) acc[o] = b[o];
    const float* inn = in + (size_t)n * in_ns;
#pragma unroll
    for (int c = 0; c < CIN; ++c) {
#pragma unroll
        for (int k = 0; k < 9; ++k) {
            int hh = h + k / 3 - 1, qq = q + k % 3 - 1;
            if (hh < 0 || hh >= WD || qq < 0 || qq >= WD) continue;
            float v = inn[c * HWD + hh * WD + qq];
            const float* wp = &wl[(c * 9 + k) * COUT];
#pragma unroll
            for (int o = 0; o < COUT; ++o) acc[o] += v * wp[o];
        }
    }
    float* op = out + ((size_t)idx) * COUT;
#pragma unroll
    for (int o = 0; o < COUT; ++o) op[o] = RELU ? fmaxf(acc[o], 0.f) : acc[o];
}

// ---------------- a1c = 1x1 conv (16 out) of feats[n+2], NHWC ----------------
__global__ void a1c_k(const float* __restrict__ feats, const float* __restrict__ w,
                      const float* __restrict__ b, float* __restrict__ a1c) {
    __shared__ float wl[CC * 16];
    for (int i = threadIdx.x; i < CC * 16; i += 256) {
        int o = i % 16, c = i / 16;
        wl[i] = w[o * CC + c];
    }
    __syncthreads();
    int idx = blockIdx.x * 256 + threadIdx.x;
    if (idx >= NJ * HWD) return;
    int n = idx / HWD, p = idx % HWD;
    const float* f = feats + ((size_t)(n + 2) * HWD + p) * CC;
    float acc[16];
#pragma unroll
    for (int o = 0; o < 16; ++o) acc[o] = b[o];
#pragma unroll
    for (int cg = 0; cg < 8; ++cg) {
        float4 v = *(const float4*)(f + cg * 4);
        const float* w0 = &wl[cg * 4 * 16];
#pragma unroll
        for (int o = 0; o < 16; ++o)
            acc[o] += v.x * w0[o] + v.y * w0[16 + o] + v.z * w0[32 + o] + v.w * w0[48 + o];
    }
    float* op = a1c + (size_t)idx * 16;
#pragma unroll
    for (int o = 0; o < 16; o += 4)
        *(float4*)(op + o) = make_float4(acc[o], acc[o+1], acc[o+2], acc[o+3]);
}

// ---------------- batched: a2 (recomputed) + agg=[mean,max] ----------------
__global__ void aggb_k(const float* __restrict__ feats, const float* __restrict__ w,
                       const float* __restrict__ b, const float* __restrict__ a1c,
                       float* __restrict__ agg, int4 xoff, int N) {
    __shared__ float wl[CC * 16];
    for (int i = threadIdx.x; i < CC * 16; i += 256) {
        int o = i % 16, c = i / 16;
        wl[i] = w[o * CC + c];
    }
    __syncthreads();
    int idx = blockIdx.x * 256 + threadIdx.x;
    if (idx >= N) return;
    int bi = idx / (NJ * HWD);
    int rem = idx - bi * (NJ * HWD);
    int n = rem / HWD, p = rem % HWD;
    int xo = sel4(xoff, bi);
    const float* f = feats + ((size_t)(n + xo) * HWD + p) * CC;
    float acc[16];
#pragma unroll
    for (int o = 0; o < 16; ++o) acc[o] = b[o];
#pragma unroll
    for (int cg = 0; cg < 8; ++cg) {
        float4 v = *(const float4*)(f + cg * 4);
        const float* w0 = &wl[cg * 4 * 16];
#pragma unroll
        for (int o = 0; o < 16; ++o)
            acc[o] += v.x * w0[o] + v.y * w0[16 + o] + v.z * w0[32 + o] + v.w * w0[48 + o];
    }
    float sum = 0.f, mx = -1e30f;
    const float* ap = a1c + (size_t)rem * 16;
#pragma unroll
    for (int o = 0; o < 16; ++o) {
        float v = ap[o];
        sum += v; mx = fmaxf(mx, v);
    }
#pragma unroll
    for (int o = 0; o < 16; ++o) {
        sum += acc[o]; mx = fmaxf(mx, acc[o]);
    }
    agg[(size_t)idx * 2 + 0] = sum * (1.f / 32.f);
    agg[(size_t)idx * 2 + 1] = mx;
}

// ---------------- batched: sig from agg 3x3; fused = [a1c*g0, a2*g1] ----------------
__global__ void sigfusedb_k(const float* __restrict__ agg, const float* __restrict__ sqw,
                            const float* __restrict__ sqb, const float* __restrict__ a1c,
                            const float* __restrict__ feats, const float* __restrict__ w,
                            const float* __restrict__ b, float* __restrict__ fused,
                            int4 xoff, int N) {
    __shared__ float wl[CC * 16];
    for (int i = threadIdx.x; i < CC * 16; i += 256) {
        int o = i % 16, c = i / 16;
        wl[i] = w[o * CC + c];
    }
    __syncthreads();
    int idx = blockIdx.x * 256 + threadIdx.x;
    if (idx >= N) return;
    int bi = idx / (NJ * HWD);
    int rem = idx - bi * (NJ * HWD);
    int n = rem / HWD, p = rem % HWD;
    int h = p / WD, q = p % WD;
    float s0 = sqb[0], s1 = sqb[1];
    const float* ag = agg + (size_t)(idx - p) * 2;  // frame base: (bi*NJ+n)*HWD*2
#pragma unroll
    for (int k = 0; k < 9; ++k) {
        int hh = h + k / 3 - 1, qq = q + k % 3 - 1;
        if (hh < 0 || hh >= WD || qq < 0 || qq >= WD) continue;
        float2 v = *(const float2*)(ag + (hh * WD + qq) * 2);
        s0 += v.x * sqw[0 * 18 + 0 * 9 + k] + v.y * sqw[0 * 18 + 1 * 9 + k];
        s1 += v.x * sqw[1 * 18 + 0 * 9 + k] + v.y * sqw[1 * 18 + 1 * 9 + k];
    }
    float g0 = sigm(s0), g1 = sigm(s1);
    int xo = sel4(xoff, bi);
    const float* f = feats + ((size_t)(n + xo) * HWD + p) * CC;
    float acc[16];
#pragma unroll
    for (int o = 0; o < 16; ++o) acc[o] = b[o];
#pragma unroll
    for (int cg = 0; cg < 8; ++cg) {
        float4 v = *(const float4*)(f + cg * 4);
        const float* w0 = &wl[cg * 4 * 16];
#pragma unroll
        for (int o = 0; o < 16; ++o)
            acc[o] += v.x * w0[o] + v.y * w0[16 + o] + v.z * w0[32 + o] + v.w * w0[48 + o];
    }
    const float* ap = a1c + (size_t)rem * 16;
    float* fp = fused + (size_t)idx * CC;
#pragma unroll
    for (int o = 0; o < 16; ++o) fp[o] = ap[o] * g0;
#pragma unroll
    for (int o = 0; o < 16; ++o) fp[16 + o] = acc[o] * g1;
}

// ---------------- batched deformable conv 3x3, 32->32, NHWC ----------------
__global__ __launch_bounds__(256, 2)
void deformb_k(const float* __restrict__ base, const float* __restrict__ off,
               const float* __restrict__ w, float* __restrict__ out,
               int4 froff, int N) {
    __shared__ float wl[9 * CC * CC];
    for (int i = threadIdx.x; i < 9 * CC * CC; i += 256) {
        int o = i & 31, c = (i >> 5) & 31, kk = i >> 10;
        wl[i] = w[(o * CC + c) * 9 + kk];
    }
    __syncthreads();
    int idx = blockIdx.x * 256 + threadIdx.x;
    if (idx >= N) return;
    int bi = idx / (NJ * HWD);
    int rem = idx - bi * (NJ * HWD);
    int n = rem / HWD, p = rem % HWD;
    int h = p / WD, q = p % WD;
    const float* xf = base + (size_t)(n + sel4(froff, bi)) * HWD * CC;
    const float* ofp = off + (size_t)idx * 18;
    float ofv[18];
#pragma unroll
    for (int i = 0; i < 18; i += 2) {
        float2 t = *(const float2*)(ofp + i);
        ofv[i] = t.x; ofv[i + 1] = t.y;
    }
    float acc[CC];
#pragma unroll
    for (int o = 0; o < CC; ++o) acc[o] = 0.f;
#pragma unroll
    for (int kk = 0; kk < 9; ++kk) {
        float py = (float)(h - 1 + kk / 3) + ofv[2 * kk];
        float px = (float)(q - 1 + kk % 3) + ofv[2 * kk + 1];
        float y0f = floorf(py), x0f = floorf(px);
        float ly = py - y0f, lx = px - x0f;
        int y0 = (int)y0f, x0 = (int)x0f;
        float w00 = (1.f - ly) * (1.f - lx), w01 = (1.f - ly) * lx;
        float w10 = ly * (1.f - lx), w11 = ly * lx;
        bool yv0 = (y0 >= 0 && y0 < WD), yv1 = (y0 + 1 >= 0 && y0 + 1 < WD);
        bool xv0 = (x0 >= 0 && x0 < WD), xv1 = (x0 + 1 >= 0 && x0 + 1 < WD);
        if (!(yv0 && xv0)) w00 = 0.f;
        if (!(yv0 && xv1)) w01 = 0.f;
        if (!(yv1 && xv0)) w10 = 0.f;
        if (!(yv1 && xv1)) w11 = 0.f;
        int yc0 = min(max(y0, 0), WD - 1), yc1 = min(max(y0 + 1, 0), WD - 1);
        int xc0 = min(max(x0, 0), WD - 1), xc1 = min(max(x0 + 1, 0), WD - 1);
        const float* p00 = xf + (yc0 * WD + xc0) * CC;
        const float* p01 = xf + (yc0 * WD + xc1) * CC;
        const float* p10 = xf + (yc1 * WD + xc0) * CC;
        const float* p11 = xf + (yc1 * WD + xc1) * CC;
        const float* wk = &wl[kk * CC * CC];
#pragma unroll
        for (int cg = 0; cg < 8; ++cg) {
            float4 a = *(const float4*)(p00 + cg * 4);
            float4 bb = *(const float4*)(p01 + cg * 4);
            float4 cc = *(const float4*)(p10 + cg * 4);
            float4 dd = *(const float4*)(p11 + cg * 4);
            float s0 = a.x * w00 + bb.x * w01 + cc.x * w10 + dd.x * w11;
            float s1 = a.y * w00 + bb.y * w01 + cc.y * w10 + dd.y * w11;
            float s2 = a.z * w00 + bb.z * w01 + cc.z * w10 + dd.z * w11;
            float s3 = a.w * w00 + bb.w * w01 + cc.w * w10 + dd.w * w11;
            const float* w0 = wk + (cg * 4) * CC;
#pragma unroll
            for (int o = 0; o < CC; ++o)
                acc[o] += s0 * w0[o] + s1 * w0[CC + o] + s2 * w0[2 * CC + o] + s3 * w0[3 * CC + o];
        }
    }
    float* op = out + (size_t)idx * CC;
#pragma unroll
    for (int o = 0; o < CC; o += 4)
        *(float4*)(op + o) = make_float4(acc[o], acc[o+1], acc[o+2], acc[o+3]);
}

// ---------------- batched 3x3 conv 32->1 into aligned channels ----------------
__global__ void convoutb_k(const float* __restrict__ in, const float* __restrict__ w,
                           const float* __restrict__ b, float* __restrict__ outA,
                           int4 cidx, int N) {
    __shared__ float wl[9 * CC];
    for (int i = threadIdx.x; i < 9 * CC; i += 256) {
        int k = i / CC, c = i % CC;
        wl[i] = w[c * 9 + k];
    }
    __syncthreads();
    int idx = blockIdx.x * 256 + threadIdx.x;
    if (idx >= N) return;
    int bi = idx / (NJ * HWD);
    int rem = idx - bi * (NJ * HWD);
    int n = rem / HWD, p = rem % HWD;
    int h = p / WD, q = p % WD;
    int fr = idx / HWD;
    const float* inn = in + (size_t)fr * HWD * CC;
    float acc = b[0];
#pragma unroll
    for (int k = 0; k < 9; ++k) {
        int hh = h + k / 3 - 1, qq = q + k % 3 - 1;
        if (hh < 0 || hh >= WD || qq < 0 || qq >= WD) continue;
        const float* ip = inn + (hh * WD + qq) * CC;
        const float* wk = &wl[k * CC];
#pragma unroll
        for (int cg = 0; cg < 8; ++cg) {
            float4 v = *(const float4*)(ip + cg * 4);
            acc += v.x * wk[cg*4] + v.y * wk[cg*4+1] + v.z * wk[cg*4+2] + v.w * wk[cg*4+3];
        }
    }
    outA[((size_t)n * 5 + sel4(cidx, bi)) * HWD + p] = acc;
}

// ---------------- cen_raw into aligned ch2 + arange output ----------------
__global__ void misc_k(const float* __restrict__ imgs, float* __restrict__ out) {
    int idx = blockIdx.x * 256 + threadIdx.x;
    float* alig = out + 135036 + 124;
    if (idx < NJ * HWD) {
        int n = idx / HWD, p = idx % HWD;
        alig[((size_t)n * 5 + 2) * HWD + p] = imgs[(size_t)(n + 2) * HWD + p];
    }
    if (idx < NJ) out[135036 + idx] = (float)(idx + 2);
}

extern "C" void kernel_launch(void* const* d_in, const int* in_sizes, int n_in,
                              void* d_out, int out_size, void* d_ws, size_t ws_size,
                              hipStream_t stream) {
    const float* x      = (const float*)d_in[0];
    const float* mlp_w  = (const float*)d_in[1];
    const float* mlp_b  = (const float*)d_in[2];
    const float* fe_w   = (const float*)d_in[3];
    const float* fe_b   = (const float*)d_in[4];
    const float* c0_w   = (const float*)d_in[5];
    const float* c0_b   = (const float*)d_in[6];
    const float* c1_w   = (const float*)d_in[7];
    const float* c1_b   = (const float*)d_in[8];
    const float* sq_w   = (const float*)d_in[9];
    const float* sq_b   = (const float*)d_in[10];
    const float* off1_w = (const float*)d_in[11];
    const float* off1_b = (const float*)d_in[12];
    const float* dw1    = (const float*)d_in[13];
    const float* off2_w = (const float*)d_in[14];
    const float* off2_b = (const float*)d_in[15];
    const float* dw2    = (const float*)d_in[16];
    const float* conv_w = (const float*)d_in[17];
    const float* conv_b = (const float*)d_in[18];
    const float* tc0_w  = (const float*)d_in[19];
    const float* tc0_b  = (const float*)d_in[20];
    const float* rb_w1  = (const float*)d_in[21];
    const float* rb_b1  = (const float*)d_in[22];
    const float* rb_w2  = (const float*)d_in[23];
    const float* rb_b2  = (const float*)d_in[24];
    const float* tail_w = (const float*)d_in[25];

    // choose batch width nb by workspace size
    const size_t FRAME = (size_t)NJ * HWD;  // 135036
    const size_t baseN = 1089 + (size_t)NF * HWD + (size_t)NF * HWD * CC + FRAME * 16;
    const size_t perB  = FRAME * 2 + FRAME * 32 + FRAME * 18 + FRAME * 32;  // agg,fused,offb,al1
    int nb = 4;
    while (nb > 1 && (baseN + (size_t)nb * perB) * 4 > ws_size) nb >>= 1;

    float* ws = (float*)d_ws;
    float* rs    = ws;
    float* imgs  = rs + 1089;
    float* feats = imgs + NF * HWD;
    float* a1c   = feats + (size_t)NF * HWD * CC;
    float* agg   = a1c + FRAME * 16;
    float* fused = agg + (size_t)nb * FRAME * 2;
    float* offb  = fused + (size_t)nb * FRAME * 32;
    float* al1   = offb + (size_t)nb * FRAME * 18;
    float* al2   = fused;            // fused dead after off1 conv
    float* hbuf  = feats;            // tail reuse
    float* tmp   = fused;            // tail reuse (>= FRAME*32)

    float* outF = (float*)d_out;
    float* outA = outF + 135036 + 124;

    const int GF = (NF * HWD + 255) / 256;
    const int GJ = (NJ * HWD + 255) / 256;

    rowsum_k<<<HWD, 256, 0, stream>>>(mlp_w, rs);
    imgs_k<<<GF, 256, 0, stream>>>(x, rs, mlp_b, imgs);
    conv3x3_chwin<1, 32, true><<<GF, 256, 0, stream>>>(imgs, HWD, fe_w, fe_b, feats, NF);
    a1c_k<<<GJ, 256, 0, stream>>>(feats, c0_w, c0_b, a1c);

    const int xoffs_all[4] = {0, 1, 3, 4};   // 2 + {-2,-1,1,2}
    const int cidx_all[4]  = {0, 1, 3, 4};
    for (int pb = 0; pb < 4; pb += nb) {
        int4 xo = make_int4(xoffs_all[pb],
                            xoffs_all[(pb + 1) & 3],
                            xoffs_all[(pb + 2) & 3],
                            xoffs_all[(pb + 3) & 3]);
        int4 ci = make_int4(cidx_all[pb],
                            cidx_all[(pb + 1) & 3],
                            cidx_all[(pb + 2) & 3],
                            cidx_all[(pb + 3) & 3]);
        int4 f2 = make_int4(0, NJ, 2 * NJ, 3 * NJ);
        int N = nb * (int)FRAME;
        int GB = (N + 255) / 256;
        aggb_k<<<GB, 256, 0, stream>>>(feats, c1_w, c1_b, a1c, agg, xo, N);
        sigfusedb_k<<<GB, 256, 0, stream>>>(agg, sq_w, sq_b, a1c, feats, c1_w, c1_b, fused, xo, N);
        conv3x3_nhwc<32, 18, false, true, false><<<GB, 256, 0, stream>>>(
            fused, off1_w, off1_b, nullptr, 0, 0, offb, 18, HWD * 18, nb * NJ);
        deformb_k<<<GB, 256, 0, stream>>>(feats, offb, dw1, al1, xo, N);
        conv3x3_nhwc<32, 18, false, true, false><<<GB, 256, 0, stream>>>(
            al1, off2_w, off2_b, nullptr, 0, 0, offb, 18, HWD * 18, nb * NJ);
        deformb_k<<<GB, 256, 0, stream>>>(al1, offb, dw2, al2, f2, N);
        convoutb_k<<<GB, 256, 0, stream>>>(al2, conv_w, conv_b, outA, ci, N);
    }

    misc_k<<<GJ, 256, 0, stream>>>(imgs, outF);

    conv3x3_chwin<5, 32, true><<<GJ, 256, 0, stream>>>(outA, 5 * HWD, tc0_w, tc0_b, hbuf, NJ);
    for (int l = 0; l < 5; ++l) {
        conv3x3_nhwc<32, 32, true, true, false><<<GJ, 256, 0, stream>>>(
            hbuf, rb_w1 + (size_t)l * CC * CC * 9, rb_b1 + l * CC,
            nullptr, 0, 0, tmp, CC, HWD * CC, NJ);
        conv3x3_nhwc<32, 32, false, true, true><<<GJ, 256, 0, stream>>>(
            tmp, rb_w2 + (size_t)l * CC * CC * 9, rb_b2 + l * CC,
            hbuf, CC, HWD * CC, hbuf, CC, HWD * CC, NJ);
    }
    conv3x3_nhwc<32, 1, false, false, false><<<GJ, 256, 0, stream>>>(
        hbuf, tail_w, nullptr, nullptr, 0, 0, outF, 1, HWD, NJ);
}